// Round 3
// baseline (17078.899 us; speedup 1.0000x reference)
//
#include <hip/hip_runtime.h>
#include <math.h>

#define BB 128
#define TT 512
#define DD 512
#define HH 512
#define NN (BB*TT)   // 65536
#define PP 512
#define AA 32
#define CH 64        // timesteps per chunk
#define CR (BB*CH)   // rows per chunk per net = 8192

typedef unsigned short u16;
typedef unsigned int   u32;
typedef __attribute__((ext_vector_type(8))) short short8;
typedef __attribute__((ext_vector_type(4))) float f32x4;

__device__ __forceinline__ u16 f2bf(float f){
    u32 x = __float_as_uint(f);
    u32 r = (x + 0x7fffu + ((x >> 16) & 1u)) >> 16;   // RNE
    return (u16)r;
}
__device__ __forceinline__ float bf2f(u16 u){
    return __uint_as_float(((u32)u) << 16);
}
__device__ __forceinline__ f32x4 mfma16(short8 a, short8 b, f32x4 c){
    return __builtin_amdgcn_mfma_f32_16x16x32_bf16(a, b, c, 0, 0, 0);
}
__device__ __forceinline__ float sigm(float x){
    return 1.f/(1.f + __expf(-x));
}
__device__ __forceinline__ float tanh_f(float x){
    return 1.f - 2.f/(1.f + __expf(2.f*x));
}

// ---------------------------------------------------------------------------
// prep LSTM weights:
//   wih planes: PERMUTED col c = u*4+g  <- src row g*512+u   (for gx float4 gate reads)
//   whh planes: UNPERMUTED (row = g*512+u, identity)         (gate = MFMA tile idx)
//   biasP: permuted bih+bhh
// ---------------------------------------------------------------------------
__global__ __launch_bounds__(256) void prep_lstm_w(
    const float* __restrict__ Wih_pi, const float* __restrict__ Whh_pi,
    const float* __restrict__ bih_pi, const float* __restrict__ bhh_pi,
    const float* __restrict__ Wih_vf, const float* __restrict__ Whh_vf,
    const float* __restrict__ bih_vf, const float* __restrict__ bhh_vf,
    u16* __restrict__ wihHi, u16* __restrict__ wihLo,
    u16* __restrict__ whhHi, u16* __restrict__ whhLo,
    float* __restrict__ biasP)
{
    long i = (long)blockIdx.x*256 + threadIdx.x;
    if (i >= 2L*2048*512) return;
    int L = (int)(i >> 20);
    int rem = (int)(i & 1048575);
    int c = rem >> 9, k = rem & 511;
    int u = c >> 2, g = c & 3;
    float wih = (L ? Wih_vf : Wih_pi)[(long)(g*512 + u)*512 + k];
    float whh = (L ? Whh_vf : Whh_pi)[(long)c*512 + k];
    u16 h1 = f2bf(wih); wihHi[i] = h1; wihLo[i] = f2bf(wih - bf2f(h1));
    u16 h2 = f2bf(whh); whhHi[i] = h2; whhLo[i] = f2bf(whh - bf2f(h2));
    if (k == 0) {
        float b = (L ? bih_vf : bih_pi)[g*512+u] + (L ? bhh_vf : bhh_pi)[g*512+u];
        biasP[L*2048 + c] = b;
    }
}

// prep MLP weight planes: mat 0=w1pi 1=w1vf 2=w2pi 3=w2vf
__global__ __launch_bounds__(256) void prep_mlp_w(
    const float* __restrict__ w1pi, const float* __restrict__ w1vf,
    const float* __restrict__ w2pi, const float* __restrict__ w2vf,
    const float* __restrict__ b1pi, const float* __restrict__ b1vf,
    const float* __restrict__ b2pi, const float* __restrict__ b2vf,
    u16* __restrict__ mHi, u16* __restrict__ mLo, float* __restrict__ biasM)
{
    long i = (long)blockIdx.x*256 + threadIdx.x;
    if (i >= 4L*262144) return;
    int mat = (int)(i >> 18);
    int rem = (int)(i & 262143);
    const float* src = mat==0 ? w1pi : mat==1 ? w1vf : mat==2 ? w2pi : w2vf;
    float v = src[rem];
    u16 h = f2bf(v); mHi[i] = h; mLo[i] = f2bf(v - bf2f(h));
    if (rem < 512) {
        const float* bs = mat==0 ? b1pi : mat==1 ? b1vf : mat==2 ? b2pi : b2vf;
        biasM[mat*512 + rem] = bs[rem];
    }
}

// init h (pre-masked by starts[t=0]) + c (pre-masked), zero barriers
__global__ __launch_bounds__(256) void init_state_k(
    const float* __restrict__ h0_pi, const float* __restrict__ c0_pi,
    const float* __restrict__ h0_vf, const float* __restrict__ c0_vf,
    const float* __restrict__ starts,
    u16* __restrict__ hHi, u16* __restrict__ hLo, float* __restrict__ cSt,
    u32* __restrict__ bar)
{
    int i = blockIdx.x*256 + threadIdx.x;
    if (i < 64) bar[i] = 0;
    if (i >= 2*BB*HH) return;
    int L = i >> 16; int r = i & 65535;
    int e = r >> 9;
    float m = 1.0f - starts[(long)e*TT];
    float h = (L ? h0_vf : h0_pi)[r] * m;
    float c = (L ? c0_vf : c0_pi)[r] * m;
    long hidx = (long)(L*2)*65536 + r;    // [L][parity=0][e][u]
    u16 hh = f2bf(h);
    hHi[hidx] = hh; hLo[hidx] = f2bf(h - bf2f(hh));
    cSt[i] = c;
}

// ---------------------------------------------------------------------------
// generic K=512 split-bf16 GEMM, tile 128x128, 256 threads (4 waves, 64x64)
// AM: 0 = A fp32 (converted in staging, row map (m>>sh)*outer+(m&mask)+base)
//     1 = A hi/lo planes
// EM: 0 = +bias -> fp32 out   1 = +bias,relu -> planes   2 = +bias -> planes
// ---------------------------------------------------------------------------
template<int AM, int EM>
__global__ __launch_bounds__(256) void gemm_k512(
    const float* __restrict__ Afp,
    const u16* __restrict__ aHi, const u16* __restrict__ aLo, long aZ,
    int rowSh, int rowOuter, int rowBase,
    const u16* __restrict__ bHi, const u16* __restrict__ bLo, long bZ,
    const float* __restrict__ bias, long biasZ,
    float* __restrict__ outF, long outFZ, int outLd,
    u16* __restrict__ oHi, u16* __restrict__ oLo, long oZ)
{
    __shared__ u16 sAh[5120], sAl[5120], sBh[5120], sBl[5120];  // 128 x 40 each
    const int tid = threadIdx.x;
    const int z = blockIdx.z;
    const long Mbase = (long)blockIdx.x * 128;
    const long Nbase = (long)blockIdx.y * 128;
    const int r2 = tid >> 1, half = tid & 1;
    const long mstage = Mbase + r2;
    const long arow = (mstage >> rowSh) * (long)rowOuter + (mstage & (((long)1<<rowSh)-1)) + rowBase;
    const long brow = Nbase + r2;
    const int wid = tid >> 6, lane = tid & 63;
    const int mh = wid & 1, nh = wid >> 1;
    const int l15 = lane & 15, quad = lane >> 4;

    f32x4 acc[4][4];
    #pragma unroll
    for (int i = 0; i < 4; ++i)
        #pragma unroll
        for (int j = 0; j < 4; ++j)
            acc[i][j] = (f32x4){0.f,0.f,0.f,0.f};

    const int sOffW = r2*40 + half*16;

    for (int kt = 0; kt < 16; ++kt) {
        const int k0 = kt*32;
        if constexpr (AM == 0) {
            const float* ap = Afp + arow*512 + k0 + half*16;
            float fv[16];
            #pragma unroll
            for (int q = 0; q < 4; ++q) *(float4*)(fv + q*4) = ((const float4*)ap)[q];
            short8 vh0, vh1, vl0, vl1;
            #pragma unroll
            for (int i = 0; i < 8; ++i){
                u16 h  = f2bf(fv[i]);   vh0[i] = (short)h;  vl0[i] = (short)f2bf(fv[i]   - bf2f(h));
                u16 h2 = f2bf(fv[8+i]); vh1[i] = (short)h2; vl1[i] = (short)f2bf(fv[8+i] - bf2f(h2));
            }
            *(short8*)(sAh + sOffW) = vh0; *(short8*)(sAh + sOffW + 8) = vh1;
            *(short8*)(sAl + sOffW) = vl0; *(short8*)(sAl + sOffW + 8) = vl1;
        } else {
            const u16* ph = aHi + (long)z*aZ + arow*512 + k0 + half*16;
            const u16* pl = aLo + (long)z*aZ + arow*512 + k0 + half*16;
            *(short8*)(sAh + sOffW) = *(const short8*)ph;
            *(short8*)(sAh + sOffW + 8) = *(const short8*)(ph + 8);
            *(short8*)(sAl + sOffW) = *(const short8*)pl;
            *(short8*)(sAl + sOffW + 8) = *(const short8*)(pl + 8);
        }
        {
            const u16* ph = bHi + (long)z*bZ + brow*512 + k0 + half*16;
            const u16* pl = bLo + (long)z*bZ + brow*512 + k0 + half*16;
            *(short8*)(sBh + sOffW) = *(const short8*)ph;
            *(short8*)(sBh + sOffW + 8) = *(const short8*)(ph + 8);
            *(short8*)(sBl + sOffW) = *(const short8*)pl;
            *(short8*)(sBl + sOffW + 8) = *(const short8*)(pl + 8);
        }
        __syncthreads();
        short8 bh[4], bl[4];
        #pragma unroll
        for (int nt = 0; nt < 4; ++nt){
            int bo = (nh*64 + nt*16 + l15)*40 + quad*8;
            bh[nt] = *(const short8*)(sBh + bo);
            bl[nt] = *(const short8*)(sBl + bo);
        }
        #pragma unroll
        for (int mt = 0; mt < 4; ++mt){
            int ao = (mh*64 + mt*16 + l15)*40 + quad*8;
            short8 ah = *(const short8*)(sAh + ao);
            short8 al = *(const short8*)(sAl + ao);
            #pragma unroll
            for (int nt = 0; nt < 4; ++nt){
                acc[mt][nt] = mfma16(ah, bh[nt], acc[mt][nt]);
                acc[mt][nt] = mfma16(ah, bl[nt], acc[mt][nt]);
                acc[mt][nt] = mfma16(al, bh[nt], acc[mt][nt]);
            }
        }
        __syncthreads();
    }
    #pragma unroll
    for (int nt = 0; nt < 4; ++nt){
        const long col = Nbase + nh*64 + nt*16 + l15;
        const float bv = bias[(long)z*biasZ + col];
        #pragma unroll
        for (int mt = 0; mt < 4; ++mt){
            const long rowm = Mbase + mh*64 + mt*16 + quad*4;
            #pragma unroll
            for (int rr = 0; rr < 4; ++rr){
                float v = acc[mt][nt][rr] + bv;
                const long m = rowm + rr;
                if constexpr (EM == 0) {
                    outF[(long)z*outFZ + m*(long)outLd + col] = v;
                } else {
                    if constexpr (EM == 1) v = fmaxf(v, 0.f);
                    u16 h = f2bf(v);
                    u16 l = f2bf(v - bf2f(h));
                    oHi[(long)z*oZ + m*512 + col] = h;
                    oLo[(long)z*oZ + m*512 + col] = l;
                }
            }
        }
    }
}

// ---------------------------------------------------------------------------
// persistent LSTM chunk: 64 steps, 128 WGs x 64 threads (1 wave each).
// WG = (L, mg: 64-env half, ug: 16-unit group). Wave tile 64 envs x 64 cols
// (4 env-tiles x 4 gate-tiles), K=512, split-bf16 (3 MFMA/frag-pair).
// Whh UNPERMUTED: gate g = B rows g*512+u -> gates land in separate
// accumulators; nonlinearity fully in registers. c-state in VGPRs.
// Steps sync via 4 independent 32-WG device-scope atomic barriers.
// ---------------------------------------------------------------------------
__global__ __launch_bounds__(64) void lstm_chunk(
    u16* __restrict__ hHi, u16* __restrict__ hLo,          // [L][2][128][512]
    const u16* __restrict__ whhHi, const u16* __restrict__ whhLo,
    const float* __restrict__ gx,                           // [L][8192][2048]
    const float* __restrict__ starts,
    float* __restrict__ cSt,                                // [L][128][512]
    u16* __restrict__ ysHi, u16* __restrict__ ysLo,         // [L][8192][512]
    float* __restrict__ dout, int t0,
    u32* __restrict__ bar)
{
    const int wg   = blockIdx.x;
    const int L    = wg >> 6;
    const int mg   = (wg >> 5) & 1;
    const int ug   = wg & 31;
    const int lane = threadIdx.x;
    const int l15  = lane & 15, quad = lane >> 4;
    const int u0   = ug * 16;
    const int gidx = L*2 + mg;
    const int ebase = mg*64;

    float creg[16];
    #pragma unroll
    for (int mt = 0; mt < 4; ++mt)
        #pragma unroll
        for (int rr = 0; rr < 4; ++rr)
            creg[mt*4+rr] = cSt[(size_t)L*65536 + (size_t)(ebase + mt*16 + quad*4 + rr)*512 + u0 + l15];

    const u16* bH = whhHi + (size_t)L*1048576 + (size_t)(u0 + l15)*512 + quad*8;
    const u16* bL = whhLo + (size_t)L*1048576 + (size_t)(u0 + l15)*512 + quad*8;

    for (int tau = 0; tau < CH; ++tau) {
        const int t = t0 + tau;
        const int p = t & 1;
        const u16* aHb = hHi + (size_t)((L*2+p)*128 + ebase + l15)*512 + quad*8;
        const u16* aLb = hLo + (size_t)((L*2+p)*128 + ebase + l15)*512 + quad*8;

        f32x4 acc[4][4];
        #pragma unroll
        for (int mt = 0; mt < 4; ++mt)
            #pragma unroll
            for (int g = 0; g < 4; ++g)
                acc[mt][g] = (f32x4){0.f,0.f,0.f,0.f};

        short8 fah[2][4], fal[2][4], fbh[2][4], fbl[2][4];
        #pragma unroll
        for (int mt = 0; mt < 4; ++mt){
            fah[0][mt] = *(const short8*)(aHb + mt*8192);
            fal[0][mt] = *(const short8*)(aLb + mt*8192);
        }
        #pragma unroll
        for (int g = 0; g < 4; ++g){
            fbh[0][g] = *(const short8*)(bH + g*262144);
            fbl[0][g] = *(const short8*)(bL + g*262144);
        }

        #pragma unroll 2
        for (int kt = 0; kt < 16; ++kt) {
            const int cur = kt & 1, nxt = cur ^ 1;
            if (kt < 15) {
                const int ko = (kt+1)*32;
                #pragma unroll
                for (int mt = 0; mt < 4; ++mt){
                    fah[nxt][mt] = *(const short8*)(aHb + mt*8192 + ko);
                    fal[nxt][mt] = *(const short8*)(aLb + mt*8192 + ko);
                }
                #pragma unroll
                for (int g = 0; g < 4; ++g){
                    fbh[nxt][g] = *(const short8*)(bH + g*262144 + ko);
                    fbl[nxt][g] = *(const short8*)(bL + g*262144 + ko);
                }
            }
            #pragma unroll
            for (int mt = 0; mt < 4; ++mt)
                #pragma unroll
                for (int g = 0; g < 4; ++g){
                    acc[mt][g] = mfma16(fah[cur][mt], fbh[cur][g], acc[mt][g]);
                    acc[mt][g] = mfma16(fah[cur][mt], fbl[cur][g], acc[mt][g]);
                    acc[mt][g] = mfma16(fal[cur][mt], fbh[cur][g], acc[mt][g]);
                }
        }

        // gates + state update, all in registers
        #pragma unroll
        for (int mt = 0; mt < 4; ++mt){
            #pragma unroll
            for (int rr = 0; rr < 4; ++rr){
                const int e = ebase + mt*16 + quad*4 + rr;
                float4 gv = *(const float4*)(gx + (size_t)L*16777216
                              + ((size_t)e*CH + tau)*2048 + (u0 + l15)*4);
                float ii = sigm(acc[mt][0][rr] + gv.x);
                float ff = sigm(acc[mt][1][rr] + gv.y);
                float gg = tanh_f(acc[mt][2][rr] + gv.z);
                float oo = sigm(acc[mt][3][rr] + gv.w);
                float cn = ff*creg[mt*4+rr] + ii*gg;
                float hn = oo * tanh_f(cn);
                float mn = (t < TT-1) ? (1.f - starts[(size_t)e*TT + t + 1]) : 1.f;
                creg[mt*4+rr] = cn * mn;
                float hm = hn * mn;
                size_t yi = ((size_t)L*CR + (size_t)e*CH + tau)*512 + u0 + l15;
                u16 yh = f2bf(hn);
                ysHi[yi] = yh; ysLo[yi] = f2bf(hn - bf2f(yh));
                size_t hi_ = ((size_t)((L*2 + (1-p))*128 + e))*512 + u0 + l15;
                u16 hh2 = f2bf(hm);
                hHi[hi_] = hh2; hLo[hi_] = f2bf(hm - bf2f(hh2));
                if (t == TT-1) {
                    dout[(size_t)(3+2*L)*NN + (size_t)e*512 + u0 + l15] = hn;
                    dout[(size_t)(4+2*L)*NN + (size_t)e*512 + u0 + l15] = cn;
                }
            }
        }

        __threadfence();
        if (lane == 0)
            __hip_atomic_fetch_add(&bar[gidx], 1u, __ATOMIC_RELEASE, __HIP_MEMORY_SCOPE_AGENT);
        if (tau < CH-1) {
            const u32 tgt = 32u * (u32)(t + 1);
            while (__hip_atomic_load(&bar[gidx], __ATOMIC_ACQUIRE, __HIP_MEMORY_SCOPE_AGENT) < tgt) {}
        }
    }

    #pragma unroll
    for (int mt = 0; mt < 4; ++mt)
        #pragma unroll
        for (int rr = 0; rr < 4; ++rr)
            cSt[(size_t)L*65536 + (size_t)(ebase + mt*16 + quad*4 + rr)*512 + u0 + l15] = creg[mt*4+rr];
}

// ---------------------------------------------------------------------------
// heads (chunk rows m = e*64+tau -> n = e*512 + t0 + (m&63))
// ---------------------------------------------------------------------------
__global__ __launch_bounds__(256) void head_pi(
    const u16* __restrict__ latHi, const u16* __restrict__ latLo,
    const float* __restrict__ actor_w, const float* __restrict__ actor_b,
    float* __restrict__ dout, int t0)
{
    __shared__ float latS[16*516];
    __shared__ float lg[16*36];
    const int tid = threadIdx.x;
    const long r0 = (long)blockIdx.x * 16;
    {
        int rr = tid >> 4, seg = tid & 15;
        const u16* ph = latHi + (r0 + rr)*512 + seg*32;
        const u16* pl = latLo + (r0 + rr)*512 + seg*32;
        float* dst = latS + rr*516 + seg*32;
        #pragma unroll
        for (int ii = 0; ii < 4; ++ii){
            short8 vh = *(const short8*)(ph + ii*8);
            short8 vl = *(const short8*)(pl + ii*8);
            #pragma unroll
            for (int jj = 0; jj < 8; ++jj)
                dst[ii*8+jj] = bf2f((u16)vh[jj]) + bf2f((u16)vl[jj]);
        }
    }
    __syncthreads();
    {
        int rr = tid >> 4, a0 = (tid & 15)*2;
        const float4* lrow = (const float4*)(latS + rr*516);
        float acc0 = actor_b[a0], acc1 = actor_b[a0+1];
        for (int kq = 0; kq < 128; ++kq){
            float4 lv = lrow[kq];
            float4 w0 = ((const float4*)actor_w)[(a0  )*128 + kq];
            float4 w1 = ((const float4*)actor_w)[(a0+1)*128 + kq];
            acc0 += lv.x*w0.x + lv.y*w0.y + lv.z*w0.z + lv.w*w0.w;
            acc1 += lv.x*w1.x + lv.y*w1.y + lv.z*w1.z + lv.w*w1.w;
        }
        lg[rr*36 + a0]   = acc0;
        lg[rr*36 + a0+1] = acc1;
    }
    __syncthreads();
    if (tid < 16){
        float mx = -INFINITY; int am = 0;
        #pragma unroll
        for (int a = 0; a < AA; ++a){
            float v = lg[tid*36 + a];
            if (v > mx){ mx = v; am = a; }
        }
        float se = 0.f;
        #pragma unroll
        for (int a = 0; a < AA; ++a) se += expf(lg[tid*36 + a] - mx);
        long row = r0 + tid;
        long n = (row >> 6)*TT + t0 + (row & 63);
        dout[n] = (float)am;
        dout[2L*NN + n] = -logf(se);
    }
}

__global__ __launch_bounds__(256) void head_vf(
    const u16* __restrict__ latHi, const u16* __restrict__ latLo,
    const float* __restrict__ critic_w, const float* __restrict__ critic_b,
    float* __restrict__ dout, int t0)
{
    __shared__ float part[256];
    const int tid = threadIdx.x;
    const long r0 = (long)blockIdx.x * 32;
    int rr = tid >> 3, seg = tid & 7;
    const u16* ph = latHi + (r0 + rr)*512 + seg*64;
    const u16* pl = latLo + (r0 + rr)*512 + seg*64;
    float acc = 0.f;
    #pragma unroll
    for (int ii = 0; ii < 8; ++ii){
        short8 vh = *(const short8*)(ph + ii*8);
        short8 vl = *(const short8*)(pl + ii*8);
        #pragma unroll
        for (int jj = 0; jj < 8; ++jj){
            float lv = bf2f((u16)vh[jj]) + bf2f((u16)vl[jj]);
            acc += lv * critic_w[seg*64 + ii*8 + jj];
        }
    }
    part[tid] = acc;
    __syncthreads();
    if (tid < 32){
        float v = critic_b[0];
        #pragma unroll
        for (int s = 0; s < 8; ++s) v += part[tid*8 + s];
        long row = r0 + tid;
        long n = (row >> 6)*TT + t0 + (row & 63);
        dout[(long)NN + n] = v;
    }
}

// ---------------------------------------------------------------------------
extern "C" void kernel_launch(void* const* d_in, const int* in_sizes, int n_in,
                              void* d_out, int out_size, void* d_ws, size_t ws_size,
                              hipStream_t stream) {
    const float* features = (const float*)d_in[0];
    const float* starts   = (const float*)d_in[1];
    const float* h0_pi = (const float*)d_in[2];
    const float* c0_pi = (const float*)d_in[3];
    const float* h0_vf = (const float*)d_in[4];
    const float* c0_vf = (const float*)d_in[5];
    const float* Wih_pi = (const float*)d_in[6];
    const float* Whh_pi = (const float*)d_in[7];
    const float* bih_pi = (const float*)d_in[8];
    const float* bhh_pi = (const float*)d_in[9];
    const float* Wih_vf = (const float*)d_in[10];
    const float* Whh_vf = (const float*)d_in[11];
    const float* bih_vf = (const float*)d_in[12];
    const float* bhh_vf = (const float*)d_in[13];
    const float* pol_w1 = (const float*)d_in[14];
    const float* pol_b1 = (const float*)d_in[15];
    const float* pol_w2 = (const float*)d_in[16];
    const float* pol_b2 = (const float*)d_in[17];
    const float* val_w1 = (const float*)d_in[18];
    const float* val_b1 = (const float*)d_in[19];
    const float* val_w2 = (const float*)d_in[20];
    const float* val_b2 = (const float*)d_in[21];
    const float* actor_w  = (const float*)d_in[22];
    const float* actor_b  = (const float*)d_in[23];
    const float* critic_w = (const float*)d_in[24];
    const float* critic_b = (const float*)d_in[25];
    float* out = (float*)d_out;

    size_t off = 0;
    auto alloc = [&](size_t b) {
        void* p = (char*)d_ws + off;
        off += (b + 255) & ~(size_t)255;
        return p;
    };
    u16* wihHi = (u16*)alloc(2L*2048*512*2);
    u16* wihLo = (u16*)alloc(2L*2048*512*2);
    u16* whhHi = (u16*)alloc(2L*2048*512*2);
    u16* whhLo = (u16*)alloc(2L*2048*512*2);
    float* biasP = (float*)alloc(2L*2048*4);
    u16* mHi = (u16*)alloc(4L*262144*2);
    u16* mLo = (u16*)alloc(4L*262144*2);
    float* biasM = (float*)alloc(4L*512*4);
    u16* hHi = (u16*)alloc(2L*2*128*512*2);
    u16* hLo = (u16*)alloc(2L*2*128*512*2);
    float* cSt = (float*)alloc(2L*128*512*4);
    u32* bar = (u32*)alloc(64*4);
    u16* ysHi = (u16*)alloc(2L*CR*512*2);
    u16* ysLo = (u16*)alloc(2L*CR*512*2);
    u16* hidHi = (u16*)alloc(2L*CR*512*2);
    u16* hidLo = (u16*)alloc(2L*CR*512*2);
    u16* latHi = (u16*)alloc(2L*CR*512*2);
    u16* latLo = (u16*)alloc(2L*CR*512*2);
    float* gxF = (float*)alloc(2L*CR*2048*4);     // [L][8192][2048], 134 MB
    const long gxZ = (long)CR*2048;               // per-net stride
    const long pZ  = (long)CR*512;                // plane per-net stride

    prep_lstm_w<<<dim3(8192), dim3(256), 0, stream>>>(
        Wih_pi, Whh_pi, bih_pi, bhh_pi, Wih_vf, Whh_vf, bih_vf, bhh_vf,
        wihHi, wihLo, whhHi, whhLo, biasP);
    prep_mlp_w<<<dim3(4096), dim3(256), 0, stream>>>(
        pol_w1, val_w1, pol_w2, val_w2, pol_b1, val_b1, pol_b2, val_b2,
        mHi, mLo, biasM);
    init_state_k<<<dim3(512), dim3(256), 0, stream>>>(
        h0_pi, c0_pi, h0_vf, c0_vf, starts, hHi, hLo, cSt, bar);

    for (int t0 = 0; t0 < TT; t0 += CH) {
        // gx = x @ Wih'^T + (bih+bhh), rows m=e*64+tau -> feature row e*512+t0+tau
        gemm_k512<0,0><<<dim3(CR/128, 16, 2), dim3(256), 0, stream>>>(
            features, nullptr, nullptr, 0L,
            6, TT, t0,
            wihHi, wihLo, 1048576L,
            biasP, 2048L,
            gxF, gxZ, 2048,
            nullptr, nullptr, 0L);
        // 64 recurrent steps, persistent
        lstm_chunk<<<dim3(128), dim3(64), 0, stream>>>(
            hHi, hLo, whhHi, whhLo, gxF, starts, cSt, ysHi, ysLo, out, t0, bar);
        // MLP layer 1 (relu) and layer 2
        gemm_k512<1,1><<<dim3(CR/128, 4, 2), dim3(256), 0, stream>>>(
            nullptr, ysHi, ysLo, pZ,
            30, 0, 0,
            mHi, mLo, 262144L,
            biasM, 512L,
            nullptr, 0L, 0,
            hidHi, hidLo, pZ);
        gemm_k512<1,2><<<dim3(CR/128, 4, 2), dim3(256), 0, stream>>>(
            nullptr, hidHi, hidLo, pZ,
            30, 0, 0,
            mHi + 2L*262144, mLo + 2L*262144, 262144L,
            biasM + 1024, 512L,
            nullptr, 0L, 0,
            latHi, latLo, pZ);
        head_pi<<<dim3(CR/16), dim3(256), 0, stream>>>(
            latHi, latLo, actor_w, actor_b, out, t0);
        head_vf<<<dim3(CR/32), dim3(256), 0, stream>>>(
            latHi + pZ, latLo + pZ, critic_w, critic_b, out, t0);
    }
}

// Round 4
// 7425.955 us; speedup vs baseline: 2.2999x; 2.2999x over previous
//
#include <hip/hip_runtime.h>
#include <math.h>

#define BB 128
#define TT 512
#define DD 512
#define HH 512
#define NN (BB*TT)   // 65536
#define PP 512
#define AA 32
#define CH 64        // timesteps per chunk
#define CR (BB*CH)   // rows per chunk per net = 8192

typedef unsigned short u16;
typedef unsigned int   u32;
typedef __attribute__((ext_vector_type(8))) short short8;
typedef __attribute__((ext_vector_type(4))) float f32x4;

__device__ __forceinline__ u16 f2bf(float f){
    u32 x = __float_as_uint(f);
    u32 r = (x + 0x7fffu + ((x >> 16) & 1u)) >> 16;   // RNE
    return (u16)r;
}
__device__ __forceinline__ float bf2f(u16 u){
    return __uint_as_float(((u32)u) << 16);
}
__device__ __forceinline__ f32x4 mfma16(short8 a, short8 b, f32x4 c){
    return __builtin_amdgcn_mfma_f32_16x16x32_bf16(a, b, c, 0, 0, 0);
}
__device__ __forceinline__ float sigm(float x){
    return 1.f/(1.f + __expf(-x));
}
__device__ __forceinline__ float tanh_f(float x){
    return 1.f - 2.f/(1.f + __expf(2.f*x));
}

// ---------------------------------------------------------------------------
// prep: permute+split LSTM weights. Both Wih and Whh PERMUTED: col c=u*4+g
// <- src row g*512+u. biasP permuted bih+bhh.
// ---------------------------------------------------------------------------
__global__ __launch_bounds__(256) void prep_lstm_w(
    const float* __restrict__ Wih_pi, const float* __restrict__ Whh_pi,
    const float* __restrict__ bih_pi, const float* __restrict__ bhh_pi,
    const float* __restrict__ Wih_vf, const float* __restrict__ Whh_vf,
    const float* __restrict__ bih_vf, const float* __restrict__ bhh_vf,
    u16* __restrict__ wihHi, u16* __restrict__ wihLo,
    u16* __restrict__ whhHi, u16* __restrict__ whhLo,
    float* __restrict__ biasP)
{
    long i = (long)blockIdx.x*256 + threadIdx.x;
    if (i >= 2L*2048*512) return;
    int L = (int)(i >> 20);
    int rem = (int)(i & 1048575);
    int c = rem >> 9, k = rem & 511;
    int u = c >> 2, g = c & 3;
    long src = (long)(g*512 + u)*512 + k;
    float wih = (L ? Wih_vf : Wih_pi)[src];
    float whh = (L ? Whh_vf : Whh_pi)[src];
    u16 h1 = f2bf(wih); wihHi[i] = h1; wihLo[i] = f2bf(wih - bf2f(h1));
    u16 h2 = f2bf(whh); whhHi[i] = h2; whhLo[i] = f2bf(whh - bf2f(h2));
    if (k == 0) {
        float b = (L ? bih_vf : bih_pi)[g*512+u] + (L ? bhh_vf : bhh_pi)[g*512+u];
        biasP[L*2048 + c] = b;
    }
}

// prep MLP weight planes: mat 0=w1pi 1=w1vf 2=w2pi 3=w2vf
__global__ __launch_bounds__(256) void prep_mlp_w(
    const float* __restrict__ w1pi, const float* __restrict__ w1vf,
    const float* __restrict__ w2pi, const float* __restrict__ w2vf,
    const float* __restrict__ b1pi, const float* __restrict__ b1vf,
    const float* __restrict__ b2pi, const float* __restrict__ b2vf,
    u16* __restrict__ mHi, u16* __restrict__ mLo, float* __restrict__ biasM)
{
    long i = (long)blockIdx.x*256 + threadIdx.x;
    if (i >= 4L*262144) return;
    int mat = (int)(i >> 18);
    int rem = (int)(i & 262143);
    const float* src = mat==0 ? w1pi : mat==1 ? w1vf : mat==2 ? w2pi : w2vf;
    float v = src[rem];
    u16 h = f2bf(v); mHi[i] = h; mLo[i] = f2bf(v - bf2f(h));
    if (rem < 512) {
        const float* bs = mat==0 ? b1pi : mat==1 ? b1vf : mat==2 ? b2pi : b2vf;
        biasM[mat*512 + rem] = bs[rem];
    }
}

// init: h planes [L][p=0][e][u] pre-masked; cT transposed [L][u][e] pre-masked;
// startsT [t][e]
__global__ __launch_bounds__(256) void init_state_k(
    const float* __restrict__ h0_pi, const float* __restrict__ c0_pi,
    const float* __restrict__ h0_vf, const float* __restrict__ c0_vf,
    const float* __restrict__ starts,
    u16* __restrict__ hHi, u16* __restrict__ hLo, float* __restrict__ cT,
    float* __restrict__ startsT)
{
    int i = blockIdx.x*256 + threadIdx.x;
    if (i < NN) {
        int e = i >> 9, t = i & 511;
        startsT[t*128 + e] = starts[i];
    }
    if (i >= 2*BB*HH) return;
    int L = i >> 16; int r = i & 65535;
    int e = r >> 9, u = r & 511;
    float m = 1.0f - starts[(long)e*TT];
    float h = (L ? h0_vf : h0_pi)[r] * m;
    float c = (L ? c0_vf : c0_pi)[r] * m;
    long hidx = (long)(L*2)*65536 + r;    // [L][parity=0][e][u]
    u16 hh = f2bf(h);
    hHi[hidx] = hh; hLo[hidx] = f2bf(h - bf2f(hh));
    cT[(long)L*65536 + (long)u*128 + e] = c;
}

// ---------------------------------------------------------------------------
// generic K=512 split-bf16 GEMM, tile 128x128, 256 threads (4 waves, 64x64)
// AM: 0 = A fp32 (converted in staging)
//     1 = A hi/lo planes
// row map: arow = (m>>rowSh)*rowOuterHi + (m&mask)*rowOuterLo + rowBase
// EM: 0 = +bias -> fp32 out   1 = +bias,relu -> planes   2 = +bias -> planes
// ---------------------------------------------------------------------------
template<int AM, int EM>
__global__ __launch_bounds__(256) void gemm_k512(
    const float* __restrict__ Afp,
    const u16* __restrict__ aHi, const u16* __restrict__ aLo, long aZ,
    int rowSh, int rowOuterHi, int rowOuterLo, int rowBase,
    const u16* __restrict__ bHi, const u16* __restrict__ bLo, long bZ,
    const float* __restrict__ bias, long biasZ,
    float* __restrict__ outF, long outFZ, int outLd,
    u16* __restrict__ oHi, u16* __restrict__ oLo, long oZ)
{
    __shared__ u16 sAh[5120], sAl[5120], sBh[5120], sBl[5120];  // 128 x 40 each
    const int tid = threadIdx.x;
    const int z = blockIdx.z;
    const long Mbase = (long)blockIdx.x * 128;
    const long Nbase = (long)blockIdx.y * 128;
    const int r2 = tid >> 1, half = tid & 1;
    const long mstage = Mbase + r2;
    const long arow = (mstage >> rowSh) * (long)rowOuterHi
                    + (mstage & (((long)1<<rowSh)-1)) * (long)rowOuterLo + rowBase;
    const long brow = Nbase + r2;
    const int wid = tid >> 6, lane = tid & 63;
    const int mh = wid & 1, nh = wid >> 1;
    const int l15 = lane & 15, quad = lane >> 4;

    f32x4 acc[4][4];
    #pragma unroll
    for (int i = 0; i < 4; ++i)
        #pragma unroll
        for (int j = 0; j < 4; ++j)
            acc[i][j] = (f32x4){0.f,0.f,0.f,0.f};

    const int sOffW = r2*40 + half*16;

    for (int kt = 0; kt < 16; ++kt) {
        const int k0 = kt*32;
        if constexpr (AM == 0) {
            const float* ap = Afp + arow*512 + k0 + half*16;
            float fv[16];
            #pragma unroll
            for (int q = 0; q < 4; ++q) *(float4*)(fv + q*4) = ((const float4*)ap)[q];
            short8 vh0, vh1, vl0, vl1;
            #pragma unroll
            for (int i = 0; i < 8; ++i){
                u16 h  = f2bf(fv[i]);   vh0[i] = (short)h;  vl0[i] = (short)f2bf(fv[i]   - bf2f(h));
                u16 h2 = f2bf(fv[8+i]); vh1[i] = (short)h2; vl1[i] = (short)f2bf(fv[8+i] - bf2f(h2));
            }
            *(short8*)(sAh + sOffW) = vh0; *(short8*)(sAh + sOffW + 8) = vh1;
            *(short8*)(sAl + sOffW) = vl0; *(short8*)(sAl + sOffW + 8) = vl1;
        } else {
            const u16* ph = aHi + (long)z*aZ + arow*512 + k0 + half*16;
            const u16* pl = aLo + (long)z*aZ + arow*512 + k0 + half*16;
            *(short8*)(sAh + sOffW) = *(const short8*)ph;
            *(short8*)(sAh + sOffW + 8) = *(const short8*)(ph + 8);
            *(short8*)(sAl + sOffW) = *(const short8*)pl;
            *(short8*)(sAl + sOffW + 8) = *(const short8*)(pl + 8);
        }
        {
            const u16* ph = bHi + (long)z*bZ + brow*512 + k0 + half*16;
            const u16* pl = bLo + (long)z*bZ + brow*512 + k0 + half*16;
            *(short8*)(sBh + sOffW) = *(const short8*)ph;
            *(short8*)(sBh + sOffW + 8) = *(const short8*)(ph + 8);
            *(short8*)(sBl + sOffW) = *(const short8*)pl;
            *(short8*)(sBl + sOffW + 8) = *(const short8*)(pl + 8);
        }
        __syncthreads();
        short8 bh[4], bl[4];
        #pragma unroll
        for (int nt = 0; nt < 4; ++nt){
            int bo = (nh*64 + nt*16 + l15)*40 + quad*8;
            bh[nt] = *(const short8*)(sBh + bo);
            bl[nt] = *(const short8*)(sBl + bo);
        }
        #pragma unroll
        for (int mt = 0; mt < 4; ++mt){
            int ao = (mh*64 + mt*16 + l15)*40 + quad*8;
            short8 ah = *(const short8*)(sAh + ao);
            short8 al = *(const short8*)(sAl + ao);
            #pragma unroll
            for (int nt = 0; nt < 4; ++nt){
                acc[mt][nt] = mfma16(ah, bh[nt], acc[mt][nt]);
                acc[mt][nt] = mfma16(ah, bl[nt], acc[mt][nt]);
                acc[mt][nt] = mfma16(al, bh[nt], acc[mt][nt]);
            }
        }
        __syncthreads();
    }
    #pragma unroll
    for (int nt = 0; nt < 4; ++nt){
        const long col = Nbase + nh*64 + nt*16 + l15;
        const float bv = bias[(long)z*biasZ + col];
        #pragma unroll
        for (int mt = 0; mt < 4; ++mt){
            const long rowm = Mbase + mh*64 + mt*16 + quad*4;
            #pragma unroll
            for (int rr = 0; rr < 4; ++rr){
                float v = acc[mt][nt][rr] + bv;
                const long m = rowm + rr;
                if constexpr (EM == 0) {
                    outF[(long)z*outFZ + m*(long)outLd + col] = v;
                } else {
                    if constexpr (EM == 1) v = fmaxf(v, 0.f);
                    u16 h = f2bf(v);
                    u16 l = f2bf(v - bf2f(h));
                    oHi[(long)z*oZ + m*512 + col] = h;
                    oLo[(long)z*oZ + m*512 + col] = l;
                }
            }
        }
    }
}

// ---------------------------------------------------------------------------
// one LSTM step, both nets. grid (64 wc, 2 eb, 2 L) x 256 threads (4 waves).
// Swapped operands: A = Whh' (permuted cols u*4+g; rows staged to LDS, shared
// by the 4 waves), B = h (per-wave direct loads, lane l15 = env).
// D: reg = gate, quad = unit_local, l15 = env -> gate math fully in registers.
// WG covers 32 gate-cols (8 units) x 64 envs. K=512 fully accumulated.
// ---------------------------------------------------------------------------
__global__ __launch_bounds__(256) void lstm_step2(
    u16* __restrict__ hHi, u16* __restrict__ hLo,           // [L][2][128][512]
    const u16* __restrict__ whhHi, const u16* __restrict__ whhLo, // [L][2048][512] permuted
    const float* __restrict__ gx,                            // [L][tau][128][2048]
    const float* __restrict__ startsT,                       // [t][128]
    float* __restrict__ cT,                                  // [L][512][128]
    u16* __restrict__ ysHi, u16* __restrict__ ysLo,          // [L][tau][128][512]
    float* __restrict__ dout, int t, int tau)
{
    __shared__ __attribute__((aligned(16))) u16 sA[2][16384];  // [plane][kt][wcol][32k]
    __shared__ float zsm[4][144];

    const int tid  = threadIdx.x;
    const int wc   = blockIdx.x;         // 0..63 : 32 gate-cols
    const int eb   = blockIdx.y;         // 0..1  : 64-env half
    const int L    = blockIdx.z;
    const int wid  = tid >> 6, lane = tid & 63;
    const int l15  = lane & 15, quad = lane >> 4;
    const int p    = t & 1;
    const int ebase = eb*64;
    const int e    = ebase + wid*16 + l15;       // this lane's env (as B row)

    // ---- stage Whh' panel: 32 wcols x 512 k x hi/lo = 64 KB
    {
        const size_t wbase = (size_t)L*1048576 + (size_t)(wc*32)*512;
        #pragma unroll
        for (int i = 0; i < 16; ++i){
            int f = tid + i*256;          // 0..4095
            int pl = f >> 11;
            int r2 = f & 2047;
            int wcol = r2 >> 6, ksg = r2 & 63;
            const u16* src = (pl ? whhLo : whhHi) + wbase + (size_t)wcol*512 + ksg*8;
            int dst = (ksg>>2)*1024 + wcol*32 + (ksg&3)*8;
            *(short8*)(sA[pl] + dst) = *(const short8*)src;
        }
    }
    __syncthreads();

    // ---- K loop: acc[mt] = gates (i,f,g,o in regs) for unit wc*8+mt*4+quad, env l15
    const u16* hHiP = hHi + (size_t)((L*2+p)*128 + e)*512 + quad*8;
    const u16* hLoP = hLo + (size_t)((L*2+p)*128 + e)*512 + quad*8;

    f32x4 acc0 = (f32x4){0.f,0.f,0.f,0.f};
    f32x4 acc1 = (f32x4){0.f,0.f,0.f,0.f};
    #pragma unroll
    for (int kt = 0; kt < 16; ++kt){
        short8 bh = *(const short8*)(hHiP + kt*32);
        short8 bl = *(const short8*)(hLoP + kt*32);
        int a0 = kt*1024 + l15*32 + quad*8;          // mt=0 rows l15, mt=1 rows 16+l15
        short8 ah0 = *(const short8*)(sA[0] + a0);
        short8 al0 = *(const short8*)(sA[1] + a0);
        short8 ah1 = *(const short8*)(sA[0] + a0 + 512);
        short8 al1 = *(const short8*)(sA[1] + a0 + 512);
        acc0 = mfma16(ah0, bh, acc0);
        acc0 = mfma16(ah0, bl, acc0);
        acc0 = mfma16(al0, bh, acc0);
        acc1 = mfma16(ah1, bh, acc1);
        acc1 = mfma16(ah1, bl, acc1);
        acc1 = mfma16(al1, bh, acc1);
    }

    // ---- gates -> state update (lane: env = l15-col of D, unit = quad, gates = regs)
    const float mn = (t < TT-1) ? (1.0f - startsT[(t+1)*128 + e]) : 1.0f;
    const size_t gxrow = ((size_t)L*CR + (size_t)tau*128 + e)*2048 + wc*32;
    #pragma unroll
    for (int mt = 0; mt < 2; ++mt){
        const int u = wc*8 + mt*4 + quad;
        float4 gv = *(const float4*)(gx + gxrow + mt*16 + quad*4);
        f32x4 z = mt ? acc1 : acc0;
        float ii = sigm(z[0] + gv.x);
        float ff = sigm(z[1] + gv.y);
        float gg = tanh_f(z[2] + gv.z);
        float oo = sigm(z[3] + gv.w);
        size_t ci = (size_t)L*65536 + (size_t)u*128 + e;
        float cn = ff*cT[ci] + ii*gg;
        float hn = oo * tanh_f(cn);
        cT[ci] = cn * mn;
        zsm[wid][l15*8 + mt*4 + quad] = hn;
        if (mt == 0) zsm[wid][128 + l15] = mn;
        if (t == TT-1) {
            dout[(size_t)(3+2*L)*NN + (size_t)e*512 + u] = hn;
            dout[(size_t)(4+2*L)*NN + (size_t)e*512 + u] = cn;
        }
    }
    __syncthreads();

    // ---- coalesced h / ys writes: role = lane>>4 (0:hHi 1:hLo 2:ysHi 3:ysLo)
    {
        const int role = quad;
        const int e2 = l15;
        const int eg = ebase + wid*16 + e2;
        float v[8];
        #pragma unroll
        for (int j = 0; j < 8; ++j) v[j] = zsm[wid][e2*8 + j];
        const float mn2 = zsm[wid][128 + e2];
        short8 pk;
        if (role < 2) {
            #pragma unroll
            for (int j = 0; j < 8; ++j){
                float hm = v[j] * mn2;
                u16 h = f2bf(hm);
                pk[j] = (short)(role == 0 ? h : f2bf(hm - bf2f(h)));
            }
            u16* dst = (role == 0 ? hHi : hLo)
                     + (size_t)((L*2 + (1-p))*128 + eg)*512 + wc*8;
            *(short8*)dst = pk;
        } else {
            #pragma unroll
            for (int j = 0; j < 8; ++j){
                u16 h = f2bf(v[j]);
                pk[j] = (short)(role == 2 ? h : f2bf(v[j] - bf2f(h)));
            }
            u16* dst = (role == 2 ? ysHi : ysLo)
                     + ((size_t)L*CR + (size_t)tau*128 + eg)*512 + wc*8;
            *(short8*)dst = pk;
        }
    }
}

// ---------------------------------------------------------------------------
// heads: chunk row m = tau*128 + e  ->  n = e*TT + t0 + tau
// ---------------------------------------------------------------------------
__global__ __launch_bounds__(256) void head_pi(
    const u16* __restrict__ latHi, const u16* __restrict__ latLo,
    const float* __restrict__ actor_w, const float* __restrict__ actor_b,
    float* __restrict__ dout, int t0)
{
    __shared__ float latS[16*516];
    __shared__ float lg[16*36];
    const int tid = threadIdx.x;
    const long r0 = (long)blockIdx.x * 16;
    {
        int rr = tid >> 4, seg = tid & 15;
        const u16* ph = latHi + (r0 + rr)*512 + seg*32;
        const u16* pl = latLo + (r0 + rr)*512 + seg*32;
        float* dst = latS + rr*516 + seg*32;
        #pragma unroll
        for (int ii = 0; ii < 4; ++ii){
            short8 vh = *(const short8*)(ph + ii*8);
            short8 vl = *(const short8*)(pl + ii*8);
            #pragma unroll
            for (int jj = 0; jj < 8; ++jj)
                dst[ii*8+jj] = bf2f((u16)vh[jj]) + bf2f((u16)vl[jj]);
        }
    }
    __syncthreads();
    {
        int rr = tid >> 4, a0 = (tid & 15)*2;
        const float4* lrow = (const float4*)(latS + rr*516);
        float acc0 = actor_b[a0], acc1 = actor_b[a0+1];
        for (int kq = 0; kq < 128; ++kq){
            float4 lv = lrow[kq];
            float4 w0 = ((const float4*)actor_w)[(a0  )*128 + kq];
            float4 w1 = ((const float4*)actor_w)[(a0+1)*128 + kq];
            acc0 += lv.x*w0.x + lv.y*w0.y + lv.z*w0.z + lv.w*w0.w;
            acc1 += lv.x*w1.x + lv.y*w1.y + lv.z*w1.z + lv.w*w1.w;
        }
        lg[rr*36 + a0]   = acc0;
        lg[rr*36 + a0+1] = acc1;
    }
    __syncthreads();
    if (tid < 16){
        float mx = -INFINITY; int am = 0;
        #pragma unroll
        for (int a = 0; a < AA; ++a){
            float v = lg[tid*36 + a];
            if (v > mx){ mx = v; am = a; }
        }
        float se = 0.f;
        #pragma unroll
        for (int a = 0; a < AA; ++a) se += expf(lg[tid*36 + a] - mx);
        long row = r0 + tid;
        long n = (row & 127)*TT + t0 + (row >> 7);
        dout[n] = (float)am;
        dout[2L*NN + n] = -logf(se);
    }
}

__global__ __launch_bounds__(256) void head_vf(
    const u16* __restrict__ latHi, const u16* __restrict__ latLo,
    const float* __restrict__ critic_w, const float* __restrict__ critic_b,
    float* __restrict__ dout, int t0)
{
    __shared__ float part[256];
    const int tid = threadIdx.x;
    const long r0 = (long)blockIdx.x * 32;
    int rr = tid >> 3, seg = tid & 7;
    const u16* ph = latHi + (r0 + rr)*512 + seg*64;
    const u16* pl = latLo + (r0 + rr)*512 + seg*64;
    float acc = 0.f;
    #pragma unroll
    for (int ii = 0; ii < 8; ++ii){
        short8 vh = *(const short8*)(ph + ii*8);
        short8 vl = *(const short8*)(pl + ii*8);
        #pragma unroll
        for (int jj = 0; jj < 8; ++jj){
            float lv = bf2f((u16)vh[jj]) + bf2f((u16)vl[jj]);
            acc += lv * critic_w[seg*64 + ii*8 + jj];
        }
    }
    part[tid] = acc;
    __syncthreads();
    if (tid < 32){
        float v = critic_b[0];
        #pragma unroll
        for (int s = 0; s < 8; ++s) v += part[tid*8 + s];
        long row = r0 + tid;
        long n = (row & 127)*TT + t0 + (row >> 7);
        dout[(long)NN + n] = v;
    }
}

// ---------------------------------------------------------------------------
extern "C" void kernel_launch(void* const* d_in, const int* in_sizes, int n_in,
                              void* d_out, int out_size, void* d_ws, size_t ws_size,
                              hipStream_t stream) {
    const float* features = (const float*)d_in[0];
    const float* starts   = (const float*)d_in[1];
    const float* h0_pi = (const float*)d_in[2];
    const float* c0_pi = (const float*)d_in[3];
    const float* h0_vf = (const float*)d_in[4];
    const float* c0_vf = (const float*)d_in[5];
    const float* Wih_pi = (const float*)d_in[6];
    const float* Whh_pi = (const float*)d_in[7];
    const float* bih_pi = (const float*)d_in[8];
    const float* bhh_pi = (const float*)d_in[9];
    const float* Wih_vf = (const float*)d_in[10];
    const float* Whh_vf = (const float*)d_in[11];
    const float* bih_vf = (const float*)d_in[12];
    const float* bhh_vf = (const float*)d_in[13];
    const float* pol_w1 = (const float*)d_in[14];
    const float* pol_b1 = (const float*)d_in[15];
    const float* pol_w2 = (const float*)d_in[16];
    const float* pol_b2 = (const float*)d_in[17];
    const float* val_w1 = (const float*)d_in[18];
    const float* val_b1 = (const float*)d_in[19];
    const float* val_w2 = (const float*)d_in[20];
    const float* val_b2 = (const float*)d_in[21];
    const float* actor_w  = (const float*)d_in[22];
    const float* actor_b  = (const float*)d_in[23];
    const float* critic_w = (const float*)d_in[24];
    const float* critic_b = (const float*)d_in[25];
    float* out = (float*)d_out;

    size_t off = 0;
    auto alloc = [&](size_t b) {
        void* p = (char*)d_ws + off;
        off += (b + 255) & ~(size_t)255;
        return p;
    };
    u16* wihHi = (u16*)alloc(2L*2048*512*2);
    u16* wihLo = (u16*)alloc(2L*2048*512*2);
    u16* whhHi = (u16*)alloc(2L*2048*512*2);
    u16* whhLo = (u16*)alloc(2L*2048*512*2);
    float* biasP = (float*)alloc(2L*2048*4);
    u16* mHi = (u16*)alloc(4L*262144*2);
    u16* mLo = (u16*)alloc(4L*262144*2);
    float* biasM = (float*)alloc(4L*512*4);
    u16* hHi = (u16*)alloc(2L*2*128*512*2);
    u16* hLo = (u16*)alloc(2L*2*128*512*2);
    float* cT  = (float*)alloc(2L*128*512*4);
    float* startsT = (float*)alloc((size_t)NN*4);
    u16* ysHi = (u16*)alloc(2L*CR*512*2);
    u16* ysLo = (u16*)alloc(2L*CR*512*2);
    u16* hidHi = (u16*)alloc(2L*CR*512*2);
    u16* hidLo = (u16*)alloc(2L*CR*512*2);
    u16* latHi = (u16*)alloc(2L*CR*512*2);
    u16* latLo = (u16*)alloc(2L*CR*512*2);
    float* gxF = (float*)alloc(2L*CR*2048*4);     // [L][tau][128][2048], 134 MB
    const long gxZ = (long)CR*2048;               // per-net stride
    const long pZ  = (long)CR*512;                // plane per-net stride

    prep_lstm_w<<<dim3(8192), dim3(256), 0, stream>>>(
        Wih_pi, Whh_pi, bih_pi, bhh_pi, Wih_vf, Whh_vf, bih_vf, bhh_vf,
        wihHi, wihLo, whhHi, whhLo, biasP);
    prep_mlp_w<<<dim3(4096), dim3(256), 0, stream>>>(
        pol_w1, val_w1, pol_w2, val_w2, pol_b1, val_b1, pol_b2, val_b2,
        mHi, mLo, biasM);
    init_state_k<<<dim3(512), dim3(256), 0, stream>>>(
        h0_pi, c0_pi, h0_vf, c0_vf, starts, hHi, hLo, cT, startsT);

    for (int t0 = 0; t0 < TT; t0 += CH) {
        // gx[L][tau][e][2048] = x @ Wih'^T + (bih+bhh); out row m = tau*128+e,
        // feature row = e*512 + t0 + tau  -> arow = (m&127)*512 + (m>>7) + t0
        gemm_k512<0,0><<<dim3(CR/128, 16, 2), dim3(256), 0, stream>>>(
            features, nullptr, nullptr, 0L,
            7, 1, 512, t0,
            wihHi, wihLo, 1048576L,
            biasP, 2048L,
            gxF, gxZ, 2048,
            nullptr, nullptr, 0L);
        // 64 recurrent steps, one launch each
        for (int tau = 0; tau < CH; ++tau) {
            lstm_step2<<<dim3(64, 2, 2), dim3(256), 0, stream>>>(
                hHi, hLo, whhHi, whhLo, gxF, startsT, cT, ysHi, ysLo,
                out, t0 + tau, tau);
        }
        // MLP layers on the chunk (rows = tau*128+e, identity map)
        gemm_k512<1,1><<<dim3(CR/128, 4, 2), dim3(256), 0, stream>>>(
            nullptr, ysHi, ysLo, pZ,
            30, 0, 1, 0,
            mHi, mLo, 262144L,
            biasM, 512L,
            nullptr, 0L, 0,
            hidHi, hidLo, pZ);
        gemm_k512<1,2><<<dim3(CR/128, 4, 2), dim3(256), 0, stream>>>(
            nullptr, hidHi, hidLo, pZ,
            30, 0, 1, 0,
            mHi + 2L*262144, mLo + 2L*262144, 262144L,
            biasM + 1024, 512L,
            nullptr, 0L, 0,
            latHi, latLo, pZ);
        head_pi<<<dim3(CR/16), dim3(256), 0, stream>>>(
            latHi, latLo, actor_w, actor_b, out, t0);
        head_vf<<<dim3(CR/32), dim3(256), 0, stream>>>(
            latHi + pZ, latLo + pZ, critic_w, critic_b, out, t0);
    }
}